// Round 10
// baseline (549.235 us; speedup 1.0000x reference)
//
#include <hip/hip_runtime.h>
#include <hip/hip_fp16.h>
#include <math.h>

#define H 128
#define FCD 256
#define BUKSH 7                    // 128 dst nodes per bucket
#define MAXBUK 512                 // supports N <= 65536

typedef _Float16 half8 __attribute__((ext_vector_type(8)));
typedef float floatx4 __attribute__((ext_vector_type(4)));

// ---------------- DPP 16-lane (row) reduction: 4 VALU adds, no LDS pipe -------
template<int CTRL>
__device__ __forceinline__ float dppadd(float x){
  return x + __int_as_float(__builtin_amdgcn_update_dpp(
      0, __float_as_int(x), CTRL, 0xf, 0xf, true));
}
__device__ __forceinline__ float grp16_sum(float x){
  x = dppadd<0x128>(x);   // row_ror:8
  x = dppadd<0x124>(x);   // row_ror:4
  x = dppadd<0x122>(x);   // row_ror:2
  x = dppadd<0x121>(x);   // row_ror:1
  return x;
}

// ---------------- generic single-block exclusive scan (nb <= 512) -------------
__global__ void k_scan512(const int* __restrict__ in, int nb,
                          int* __restrict__ out1, int* __restrict__ out2){
  int t = threadIdx.x, lane = t & 63, w = t >> 6;
  int v = (t<nb) ? in[t] : 0;
  int x = v;
  #pragma unroll
  for (int off=1; off<64; off<<=1){
    int y = __shfl_up(x, off);
    if (lane >= off) x += y;
  }
  __shared__ int ws[8];
  if (lane==63) ws[w] = x;
  __syncthreads();
  int wo = 0;
  #pragma unroll
  for (int i=0;i<8;i++) if (i<w) wo += ws[i];
  int excl = wo + x - v;
  if (t<nb){ out1[t] = excl; if (out2) out2[t] = excl; }
  if (t==511) out1[nb] = wo + x;
}

// ---------------- bucketed CSR build ----------------
// phase 1: bucket histogram (8192 edges per block)
__global__ void k_bhist(const int* __restrict__ ei, int E, int Et, int nbuk,
                        int* __restrict__ bhist){
  __shared__ int lh[MAXBUK];
  int t = threadIdx.x;
  lh[t] = 0;
  __syncthreads();
  int j0 = blockIdx.x*8192;
  #pragma unroll
  for (int i=0;i<16;i++){
    int j = j0 + i*512 + t;
    if (j < Et){
      int dst = (j < E) ? ei[E+j] : (j - E);
      atomicAdd(&lh[dst>>BUKSH], 1);
    }
  }
  __syncthreads();
  if (t < nbuk && lh[t]) atomicAdd(&bhist[t], lh[t]);
}

// phase 2: scatter packed edges into bucket-contiguous ebuf
__global__ void k_bscatter(const int* __restrict__ ei, int E, int Et, int nbuk,
                           int* __restrict__ bnext, unsigned* __restrict__ ebuf){
  __shared__ int lh[MAXBUK];
  __shared__ int lbase[MAXBUK];
  int t = threadIdx.x;
  lh[t] = 0;
  __syncthreads();
  int j0 = blockIdx.x*8192;
  unsigned pk[16]; int bk[16]; int rk[16];
  #pragma unroll
  for (int i=0;i<16;i++){
    int j = j0 + i*512 + t;
    if (j < Et){
      int src, dst;
      if (j < E){ src = ei[j]; dst = ei[E+j]; } else { src = dst = j - E; }
      pk[i] = (unsigned)src | ((unsigned)dst << 16);
      bk[i] = dst >> BUKSH;
      rk[i] = atomicAdd(&lh[bk[i]], 1);
    }
  }
  __syncthreads();
  if (t < nbuk){
    int c = lh[t];
    lbase[t] = c ? atomicAdd(&bnext[t], c) : 0;
  }
  __syncthreads();
  #pragma unroll
  for (int i=0;i<16;i++){
    int j = j0 + i*512 + t;
    if (j < Et) ebuf[lbase[bk[i]] + rk[i]] = pk[i];
  }
}

// phase 3 (R10 fusion): bucket b's edges occupy ebuf[bbase[b]:bbase[b+1]],
// which is EXACTLY its CSR range. One kernel does: per-node count (LDS),
// 128-wide scan -> row_ptr/deg/degree-histogram, then CSR fill with LDS
// rank atomics. Replaces k_bdeg+k_scanA+k_scan512+k_scanC+k_bcsr+k_dhistM.
__global__ void k_bfill(const unsigned* __restrict__ ebuf, const int* __restrict__ bbase,
                        int N, int Et,
                        int* __restrict__ row_ptr, int* __restrict__ deg,
                        int* __restrict__ csr, int* __restrict__ hists){
  __shared__ int cnt[1<<BUKSH];
  __shared__ int lnxt[1<<BUKSH];
  __shared__ int bh[256];
  __shared__ int ws0[1];
  int b = blockIdx.x, t = threadIdx.x;
  if (t < (1<<BUKSH)) cnt[t] = 0;
  bh[t] = 0;
  if (b==0 && t==0) row_ptr[N] = Et;      // R8 fix carried forward
  __syncthreads();
  int lo = bbase[b], hi = bbase[b+1];
  for (int j = lo + t; j < hi; j += 256){
    unsigned d = ebuf[j] >> 16;
    atomicAdd(&cnt[d & ((1<<BUKSH)-1)], 1);
  }
  __syncthreads();
  // 128-wide inclusive scan (2 waves)
  int lane = t & 63;
  int v = (t < (1<<BUKSH)) ? cnt[t] : 0;
  int x = v;
  #pragma unroll
  for (int off=1; off<64; off<<=1){
    int y = __shfl_up(x, off);
    if (lane >= off) x += y;
  }
  if (t==63) ws0[0] = x;
  __syncthreads();
  if (t >= 64 && t < 128) x += ws0[0];
  if (t < (1<<BUKSH)){
    int node = (b<<BUKSH) + t;
    int excl = lo + x - v;
    lnxt[t] = excl;
    if (node < N){
      row_ptr[node] = excl;
      deg[node] = v;
      atomicAdd(&bh[min(v,255)], 1);     // per-bucket degree histogram
    }
  }
  __syncthreads();
  hists[b*256 + t] = bh[t];
  for (int j = lo + t; j < hi; j += 256){
    unsigned e = ebuf[j];
    int d = (e >> 16) & ((1<<BUKSH)-1);
    int r = atomicAdd(&lnxt[d], 1);
    csr[r] = e & 0xffff;
  }
}

// ------- degree sort (zero global atomics): column scan + block-local ranks ---
__global__ void k_dcolscan(int* __restrict__ hists, int nb, int* __restrict__ bintot){
  int d = threadIdx.x;
  int run = 0;
  for (int b=0; b<nb; b++){
    int v = hists[b*256 + d];
    hists[b*256 + d] = run;
    run += v;
  }
  bintot[d] = run;
}

__global__ void k_dscatter2(const int* __restrict__ deg, int N,
                            const int* __restrict__ hists, const int* __restrict__ base,
                            int* __restrict__ perm){
  __shared__ int lh[256];
  int t = threadIdx.x, b = blockIdx.x;   // 128 threads, one bucket per block
  lh[t] = 0; lh[t+128] = 0;
  __syncthreads();
  int i = (b<<BUKSH) + t;
  if (i < N){
    int d = min(deg[i],255);
    int r = atomicAdd(&lh[d], 1);
    perm[base[d] + hists[b*256 + d] + r] = i;
  }
}

// ------------- weight prep: Wl/Wr (128x128 f32, k-major) -> Wt fp16 [L][n][k] --
__global__ void k_prep(const float* __restrict__ Wl1, const float* __restrict__ Wr1,
                       const float* __restrict__ Wl2, const float* __restrict__ Wr2,
                       _Float16* __restrict__ Wt){
  int idx = blockIdx.x*256 + threadIdx.x;   // 2*256*128 = 65536 total
  int L   = idx >> 15;
  int rem = idx & 32767;
  int nn  = rem >> 7;        // 0..255
  int k   = rem & 127;
  const float* W = (L==0) ? (nn<H?Wl1:Wr1) : (nn<H?Wl2:Wr2);
  Wt[idx] = (_Float16)W[k*H + (nn&127)];
}

// ---------------- layer-0 K=7 GEMM pair: x fp32 -> xl/xr fp16 ----------------
__global__ void k_gemm7(const float* __restrict__ x,
                        const float* __restrict__ Wl, const float* __restrict__ bl,
                        const float* __restrict__ Wr, const float* __restrict__ br,
                        __half* __restrict__ xl, __half* __restrict__ xr, int n){
  int col = threadIdx.x;            // 0..127
  int n0 = blockIdx.x*8;
  float accl[8], accr[8];
  float bL = bl[col], bR = br[col];
  #pragma unroll
  for (int t=0;t<8;t++){ accl[t]=bL; accr[t]=bR; }
  #pragma unroll
  for (int k=0;k<7;k++){
    float wl = Wl[k*H + col];
    float wr = Wr[k*H + col];
    #pragma unroll
    for (int t=0;t<8;t++){
      int node = n0+t; if (node >= n) node = n-1;
      float hv = x[(size_t)node*7 + k];
      accl[t] = fmaf(hv, wl, accl[t]);
      accr[t] = fmaf(hv, wr, accr[t]);
    }
  }
  #pragma unroll
  for (int t=0;t<8;t++){
    int node = n0+t;
    if (node < n){
      xl[(size_t)node*H + col] = __float2half(accl[t]);
      xr[(size_t)node*H + col] = __float2half(accr[t]);
    }
  }
}

// ------------- MFMA GEMM pair: h[n,128]f16 @ Wt -> xl,xr f16 (f32 accum) ------
__global__ __launch_bounds__(256) void k_gemm2h(
    const __half* __restrict__ h, const _Float16* __restrict__ Wt,
    const float* __restrict__ bl, const float* __restrict__ br,
    __half* __restrict__ xl, __half* __restrict__ xr, int n){
  int wave = threadIdx.x >> 6, lane = threadIdx.x & 63;
  int m16 = lane & 15, quad = lane >> 4;
  int row0 = blockIdx.x*64 + wave*16;
  int arow = row0 + m16; if (arow >= n) arow = n-1;
  const __half* hr = h + (size_t)arow*H;
  half8 a[4];
  #pragma unroll
  for (int kb=0;kb<4;kb++) a[kb] = *(const half8*)(hr + kb*32 + quad*8);
  floatx4 acc[16];
  #pragma unroll
  for (int t=0;t<16;t++){ floatx4 z = {0.f,0.f,0.f,0.f}; acc[t] = z; }
  #pragma unroll
  for (int nt=0;nt<16;nt++){
    const _Float16* wr_ = Wt + (size_t)(nt*16 + m16)*H;
    #pragma unroll
    for (int kb=0;kb<4;kb++){
      half8 b = *(const half8*)(wr_ + kb*32 + quad*8);
      acc[nt] = __builtin_amdgcn_mfma_f32_16x16x32_f16(a[kb], b, acc[nt], 0,0,0);
    }
  }
  #pragma unroll
  for (int nt=0;nt<16;nt++){
    int c = nt*16 + m16;                 // D col = lane&15
    float bias; __half* dst; int cc;
    if (c < H){ bias = bl[c];   dst = xl; cc = c;   }
    else      { bias = br[c-H]; dst = xr; cc = c-H; }
    #pragma unroll
    for (int r=0;r<4;r++){
      int rw = row0 + quad*4 + r;        // D row = quad*4 + r
      if (rw < n) dst[(size_t)rw*H + cc] = __float2half(acc[nt][r] + bias);
    }
  }
}

// ------------- GATv2: 16 lanes/node, 8 feats/lane, unroll-8, fp32 edge math ---
__global__ void k_gat(const __half* __restrict__ xl, const __half* __restrict__ xr,
                      const float* __restrict__ att, const float* __restrict__ bo,
                      const int* __restrict__ row_ptr, const int* __restrict__ csr_src,
                      const int* __restrict__ perm,
                      __half* __restrict__ hout, int n){
  int gid0 = (int)((blockIdx.x*blockDim.x + threadIdx.x) >> 4);
  int lane16 = threadIdx.x & 15;
  if (gid0 >= n) return;
  int gid = perm[gid0];                  // degree-sorted order
  int f = lane16*8;
  float xrv[8], av[8];
  {
    union { float4 q; __half2 h[4]; } U;
    U.q = *(const float4*)(xr + (size_t)gid*H + f);
    #pragma unroll
    for (int i=0;i<4;i++){ float2 t2 = __half22float2(U.h[i]); xrv[2*i]=t2.x; xrv[2*i+1]=t2.y; }
    float4 a0 = *(const float4*)(att + f);
    float4 a1 = *(const float4*)(att + f + 4);
    av[0]=a0.x; av[1]=a0.y; av[2]=a0.z; av[3]=a0.w;
    av[4]=a1.x; av[5]=a1.y; av[6]=a1.z; av[7]=a1.w;
  }
  float acc[8];
  #pragma unroll
  for (int i=0;i<8;i++) acc[i]=0.f;
  float mmax = -INFINITY, denom = 0.f;
  int beg = row_ptr[gid], end = row_ptr[gid+1];
  int j = beg;
  for (; j+7 < end; j += 8){
    int s[8];
    #pragma unroll
    for (int u=0;u<8;u++) s[u] = csr_src[j+u];
    float4 r[8];
    #pragma unroll
    for (int u=0;u<8;u++) r[u] = *(const float4*)(xl + (size_t)s[u]*H + f);
    float d[8];
    #pragma unroll
    for (int u=0;u<8;u++){
      union { float4 q; __half2 h[4]; } U; U.q = r[u];
      float dd = 0.f;
      #pragma unroll
      for (int i=0;i<4;i++){
        float2 vf = __half22float2(U.h[i]);
        float u0 = vf.x + xrv[2*i];
        float u1 = vf.y + xrv[2*i+1];
        float l0 = fmaf(0.4f, fabsf(u0), 0.6f*u0);   // leaky_relu(u,0.2)
        float l1 = fmaf(0.4f, fabsf(u1), 0.6f*u1);
        dd = fmaf(l0, av[2*i], fmaf(l1, av[2*i+1], dd));
      }
      d[u] = dd;
    }
    #pragma unroll
    for (int u=0;u<8;u++) d[u] = grp16_sum(d[u]);
    float m8 = fmaxf(fmaxf(fmaxf(d[0],d[1]), fmaxf(d[2],d[3])),
                     fmaxf(fmaxf(d[4],d[5]), fmaxf(d[6],d[7])));
    if (m8 > mmax){
      float sc = __expf(mmax - m8);
      #pragma unroll
      for (int i=0;i<8;i++) acc[i] *= sc;
      denom *= sc;
      mmax = m8;
    }
    #pragma unroll
    for (int u=0;u<8;u++){
      float w = __expf(d[u] - mmax);
      denom += w;
      union { float4 q; __half2 h[4]; } U; U.q = r[u];
      #pragma unroll
      for (int i=0;i<4;i++){
        float2 vf = __half22float2(U.h[i]);
        acc[2*i]   = fmaf(w, vf.x, acc[2*i]);
        acc[2*i+1] = fmaf(w, vf.y, acc[2*i+1]);
      }
    }
  }
  for (; j<end; j++){
    int s0 = csr_src[j];
    union { float4 q; __half2 h[4]; } U;
    U.q = *(const float4*)(xl + (size_t)s0*H + f);
    float v0[8];
    #pragma unroll
    for (int i=0;i<4;i++){ float2 t0 = __half22float2(U.h[i]); v0[2*i]=t0.x; v0[2*i+1]=t0.y; }
    float dd = 0.f;
    #pragma unroll
    for (int i=0;i<8;i++){
      float u0 = v0[i] + xrv[i];
      float l0 = fmaf(0.4f, fabsf(u0), 0.6f*u0);
      dd = fmaf(l0, av[i], dd);
    }
    dd = grp16_sum(dd);
    if (dd > mmax){
      float sc = __expf(mmax - dd);
      #pragma unroll
      for (int i=0;i<8;i++) acc[i] *= sc;
      denom *= sc;
      mmax = dd;
    }
    float w = __expf(dd - mmax);
    denom += w;
    #pragma unroll
    for (int i=0;i<8;i++) acc[i] = fmaf(w, v0[i], acc[i]);
  }
  float inv = 1.f/denom;
  float o[8];
  {
    float4 b0 = *(const float4*)(bo + f);
    float4 b1 = *(const float4*)(bo + f + 4);
    float bb[8] = {b0.x,b0.y,b0.z,b0.w,b1.x,b1.y,b1.z,b1.w};
    #pragma unroll
    for (int i=0;i<8;i++){
      float t = acc[i]*inv + bb[i];
      o[i] = t > 0.f ? t : expm1f(t);   // ELU
    }
  }
  union { float4 f4; __half2 h2[4]; } u;
  #pragma unroll
  for (int i=0;i<4;i++) u.h2[i] = __floats2half2_rn(o[2*i], o[2*i+1]);
  *(float4*)(hout + (size_t)gid*H + f) = u.f4;
}

// --------- fused segment mean-pool (sorted batch, binary search) + MLP head ---
__global__ void k_fc(const __half* __restrict__ hbuf, const int* __restrict__ batch, int N,
                     const float* __restrict__ W1, const float* __restrict__ b1,
                     const float* __restrict__ W2, const float* __restrict__ b2,
                     float* __restrict__ out){
  __shared__ float g[H];
  __shared__ float2 part[4][64];
  __shared__ float zs[FCD];
  __shared__ int bounds[2];
  int gi = blockIdx.x;
  int t = threadIdx.x;     // 0..255
  if (t < 2){
    int target = gi + t;
    int lo = 0, hi = N;
    while (lo < hi){ int mid = (lo+hi)>>1; if (batch[mid] < target) lo = mid+1; else hi = mid; }
    bounds[t] = lo;
  }
  __syncthreads();
  int lo = bounds[0], hi = bounds[1];
  int pairc = t & 63, slice = t >> 6;
  float sx = 0.f, sy = 0.f;
  for (int node = lo + slice; node < hi; node += 4){
    float2 f2 = __half22float2(*(const __half2*)(hbuf + (size_t)node*H + pairc*2));
    sx += f2.x; sy += f2.y;
  }
  part[slice][pairc] = make_float2(sx, sy);
  __syncthreads();
  if (t < 64){
    float2 a = part[0][t], b = part[1][t], c = part[2][t], d = part[3][t];
    float cnt = (float)(hi - lo); if (cnt < 1.f) cnt = 1.f;
    float inv = 1.f/cnt;
    g[2*t]   = (a.x+b.x+c.x+d.x)*inv;
    g[2*t+1] = (a.y+b.y+c.y+d.y)*inv;
  }
  __syncthreads();
  float acc = b1[t];
  for (int k=0;k<H;k++) acc = fmaf(g[k], W1[k*FCD+t], acc);
  zs[t] = acc > 0.f ? acc : 0.f;
  __syncthreads();
  if (t < 2){
    float l = b2[t];
    for (int k=0;k<FCD;k++) l = fmaf(zs[k], W2[k*2+t], l);
    g[t] = l;
  }
  __syncthreads();
  if (t < 2){
    float l0 = g[0], l1 = g[1];
    float mx = fmaxf(l0,l1);
    float lse = mx + logf(__expf(l0-mx) + __expf(l1-mx));
    out[gi*2+t] = g[t] - lse;
  }
}

extern "C" void kernel_launch(void* const* d_in, const int* in_sizes, int n_in,
                              void* d_out, int out_size, void* d_ws, size_t ws_size,
                              hipStream_t stream) {
  const float* x     = (const float*)d_in[0];
  const int*   ei    = (const int*)  d_in[1];
  const int*   batch = (const int*)  d_in[2];
  const float* Wl[3]  = {(const float*)d_in[3],  (const float*)d_in[9],  (const float*)d_in[15]};
  const float* bl[3]  = {(const float*)d_in[4],  (const float*)d_in[10], (const float*)d_in[16]};
  const float* Wr[3]  = {(const float*)d_in[5],  (const float*)d_in[11], (const float*)d_in[17]};
  const float* br[3]  = {(const float*)d_in[6],  (const float*)d_in[12], (const float*)d_in[18]};
  const float* att[3] = {(const float*)d_in[7],  (const float*)d_in[13], (const float*)d_in[19]};
  const float* bo[3]  = {(const float*)d_in[8],  (const float*)d_in[14], (const float*)d_in[20]};
  const float* fc1W = (const float*)d_in[21];
  const float* fc1b = (const float*)d_in[22];
  const float* fc2W = (const float*)d_in[23];
  const float* fc2b = (const float*)d_in[24];

  const int N  = in_sizes[2];
  const int E  = in_sizes[1]/2;
  const int Et = E + N;
  const int G  = out_size/2;
  const int NBUK = (N + (1<<BUKSH)-1) >> BUKSH;   // dst buckets (<=512)
  const int NEB = (Et + 8191)/8192;        // edge blocks for bucket kernels

  char* p = (char*)d_ws;
  auto alloc = [&](size_t bytes)->void*{
    void* r = (void*)p; p += (bytes + 255) & ~(size_t)255; return r;
  };
  int*      deg     = (int*)     alloc((size_t)N*4);
  int*      row_ptr = (int*)     alloc((size_t)(N+1)*4);
  int*      bhist   = (int*)     alloc((size_t)(MAXBUK+1)*4);
  int*      bbase   = (int*)     alloc((size_t)(MAXBUK+1)*4);
  int*      bnext   = (int*)     alloc((size_t)(MAXBUK+1)*4);
  int*      hists   = (int*)     alloc((size_t)MAXBUK*256*4);
  int*      bintot  = (int*)     alloc((size_t)260*4);
  int*      dbase   = (int*)     alloc((size_t)260*4);
  int*      perm    = (int*)     alloc((size_t)N*4);
  int*      csr     = (int*)     alloc((size_t)Et*4);
  unsigned* ebuf    = (unsigned*)alloc((size_t)Et*4);
  __half*   xl      = (__half*)  alloc((size_t)N*H*2);
  __half*   xr      = (__half*)  alloc((size_t)N*H*2);
  __half*   hbuf    = (__half*)  alloc((size_t)N*H*2);
  _Float16* Wt      = (_Float16*)alloc((size_t)2*256*H*2);

  (void)hipMemsetAsync(bhist, 0, (size_t)(MAXBUK+1)*4, stream);
  k_prep<<<256, 256, 0, stream>>>(Wl[1], Wr[1], Wl[2], Wr[2], Wt);

  // ---- bucketed CSR build (fused) ----
  k_bhist   <<<NEB, 512, 0, stream>>>(ei, E, Et, NBUK, bhist);
  k_scan512 <<<1, 512, 0, stream>>>(bhist, NBUK, bbase, bnext);
  k_bscatter<<<NEB, 512, 0, stream>>>(ei, E, Et, NBUK, bnext, ebuf);
  k_bfill   <<<NBUK, 256, 0, stream>>>(ebuf, bbase, N, Et, row_ptr, deg, csr, hists);
  // ---- degree sort -> perm (zero global atomics) ----
  k_dcolscan<<<1, 256, 0, stream>>>(hists, NBUK, bintot);
  k_scan512 <<<1, 512, 0, stream>>>(bintot, 256, dbase, nullptr);
  k_dscatter2<<<NBUK, 128, 0, stream>>>(deg, N, hists, dbase, perm);

  const int g7  = (N + 7)/8;
  const int gM  = (N + 63)/64;
  const int gg  = (int)(((size_t)N*16 + 255)/256);

  // layer 0 (K=7)
  k_gemm7<<<g7, 128, 0, stream>>>(x, Wl[0], bl[0], Wr[0], br[0], xl, xr, N);
  k_gat<<<gg, 256, 0, stream>>>(xl, xr, att[0], bo[0], row_ptr, csr, perm, hbuf, N);
  // layer 1
  k_gemm2h<<<gM, 256, 0, stream>>>(hbuf, Wt, bl[1], br[1], xl, xr, N);
  k_gat<<<gg, 256, 0, stream>>>(xl, xr, att[1], bo[1], row_ptr, csr, perm, hbuf, N);
  // layer 2
  k_gemm2h<<<gM, 256, 0, stream>>>(hbuf, Wt + (size_t)256*H, bl[2], br[2], xl, xr, N);
  k_gat<<<gg, 256, 0, stream>>>(xl, xr, att[2], bo[2], row_ptr, csr, perm, hbuf, N);

  // fused pool + head (sorted batch, no atomics)
  k_fc<<<G, 256, 0, stream>>>(hbuf, batch, N, fc1W, fc1b, fc2W, fc2b, (float*)d_out);
}

// Round 11
// 460.640 us; speedup vs baseline: 1.1923x; 1.1923x over previous
//
#include <hip/hip_runtime.h>
#include <hip/hip_fp16.h>
#include <math.h>

#define H 128
#define FCD 256
#define BUKSH 7                    // 128 dst nodes per bucket
#define MAXBUK 512                 // supports N <= 65536

typedef _Float16 half8 __attribute__((ext_vector_type(8)));
typedef float floatx4 __attribute__((ext_vector_type(4)));

// ---------------- DPP 16-lane (row) reduction: 4 VALU adds, no LDS pipe -------
template<int CTRL>
__device__ __forceinline__ float dppadd(float x){
  return x + __int_as_float(__builtin_amdgcn_update_dpp(
      0, __float_as_int(x), CTRL, 0xf, 0xf, true));
}
__device__ __forceinline__ float grp16_sum(float x){
  x = dppadd<0x128>(x);   // row_ror:8
  x = dppadd<0x124>(x);   // row_ror:4
  x = dppadd<0x122>(x);   // row_ror:2
  x = dppadd<0x121>(x);   // row_ror:1
  return x;
}

// ---------------- generic single-block exclusive scan (nb <= 512) -------------
__global__ void k_scan512(const int* __restrict__ in, int nb,
                          int* __restrict__ out1, int* __restrict__ out2){
  int t = threadIdx.x, lane = t & 63, w = t >> 6;
  int v = (t<nb) ? in[t] : 0;
  int x = v;
  #pragma unroll
  for (int off=1; off<64; off<<=1){
    int y = __shfl_up(x, off);
    if (lane >= off) x += y;
  }
  __shared__ int ws[8];
  if (lane==63) ws[w] = x;
  __syncthreads();
  int wo = 0;
  #pragma unroll
  for (int i=0;i<8;i++) if (i<w) wo += ws[i];
  int excl = wo + x - v;
  if (t<nb){ out1[t] = excl; if (out2) out2[t] = excl; }
  if (t==511) out1[nb] = wo + x;
}

// ---------------- bucketed CSR build ----------------
// phase 1: bucket histogram (8192 edges per block)
__global__ void k_bhist(const int* __restrict__ ei, int E, int Et, int nbuk,
                        int* __restrict__ bhist){
  __shared__ int lh[MAXBUK];
  int t = threadIdx.x;
  lh[t] = 0;
  __syncthreads();
  int j0 = blockIdx.x*8192;
  #pragma unroll
  for (int i=0;i<16;i++){
    int j = j0 + i*512 + t;
    if (j < Et){
      int dst = (j < E) ? ei[E+j] : (j - E);
      atomicAdd(&lh[dst>>BUKSH], 1);
    }
  }
  __syncthreads();
  if (t < nbuk && lh[t]) atomicAdd(&bhist[t], lh[t]);
}

// phase 2: scatter packed edges into bucket-contiguous ebuf
__global__ void k_bscatter(const int* __restrict__ ei, int E, int Et, int nbuk,
                           int* __restrict__ bnext, unsigned* __restrict__ ebuf){
  __shared__ int lh[MAXBUK];
  __shared__ int lbase[MAXBUK];
  int t = threadIdx.x;
  lh[t] = 0;
  __syncthreads();
  int j0 = blockIdx.x*8192;
  unsigned pk[16]; int bk[16]; int rk[16];
  #pragma unroll
  for (int i=0;i<16;i++){
    int j = j0 + i*512 + t;
    if (j < Et){
      int src, dst;
      if (j < E){ src = ei[j]; dst = ei[E+j]; } else { src = dst = j - E; }
      pk[i] = (unsigned)src | ((unsigned)dst << 16);
      bk[i] = dst >> BUKSH;
      rk[i] = atomicAdd(&lh[bk[i]], 1);
    }
  }
  __syncthreads();
  if (t < nbuk){
    int c = lh[t];
    lbase[t] = c ? atomicAdd(&bnext[t], c) : 0;
  }
  __syncthreads();
  #pragma unroll
  for (int i=0;i<16;i++){
    int j = j0 + i*512 + t;
    if (j < Et) ebuf[lbase[bk[i]] + rk[i]] = pk[i];
  }
}

// phase 3 (fused): bucket b's edges occupy ebuf[bbase[b]:bbase[b+1]] == its CSR
// range. count(LDS) -> 128-wide scan -> row_ptr/deg/degree-hist(T) -> CSR fill.
__global__ void k_bfill(const unsigned* __restrict__ ebuf, const int* __restrict__ bbase,
                        int N, int Et,
                        int* __restrict__ row_ptr, int* __restrict__ deg,
                        int* __restrict__ csr, int* __restrict__ histsT){
  __shared__ int cnt[1<<BUKSH];
  __shared__ int lnxt[1<<BUKSH];
  __shared__ int bh[256];
  __shared__ int ws0[1];
  int b = blockIdx.x, t = threadIdx.x;
  if (t < (1<<BUKSH)) cnt[t] = 0;
  bh[t] = 0;
  if (b==0 && t==0) row_ptr[N] = Et;      // R8 fix carried forward
  __syncthreads();
  int lo = bbase[b], hi = bbase[b+1];
  for (int j = lo + t; j < hi; j += 256){
    unsigned d = ebuf[j] >> 16;
    atomicAdd(&cnt[d & ((1<<BUKSH)-1)], 1);
  }
  __syncthreads();
  // 128-wide inclusive scan (2 waves)
  int lane = t & 63;
  int v = (t < (1<<BUKSH)) ? cnt[t] : 0;
  int x = v;
  #pragma unroll
  for (int off=1; off<64; off<<=1){
    int y = __shfl_up(x, off);
    if (lane >= off) x += y;
  }
  if (t==63) ws0[0] = x;
  __syncthreads();
  if (t >= 64 && t < 128) x += ws0[0];
  if (t < (1<<BUKSH)){
    int node = (b<<BUKSH) + t;
    int excl = lo + x - v;
    lnxt[t] = excl;
    if (node < N){
      row_ptr[node] = excl;
      deg[node] = v;
      atomicAdd(&bh[min(v,255)], 1);     // per-bucket degree histogram
    }
  }
  __syncthreads();
  histsT[t*MAXBUK + b] = bh[t];          // TRANSPOSED: bin-major for k_dbinscan
  for (int j = lo + t; j < hi; j += 256){
    unsigned e = ebuf[j];
    int d = (e >> 16) & ((1<<BUKSH)-1);
    int r = atomicAdd(&lnxt[d], 1);
    csr[r] = e & 0xffff;
  }
}

// ------- degree sort: parallel per-bin scan (R11 — replaces serial colscan) ---
// one block per degree bin d; 512-thread shuffle scan over buckets b.
__global__ void k_dbinscan(int* __restrict__ histsT, int nb, int* __restrict__ bintot){
  int d = blockIdx.x;
  int t = threadIdx.x, lane = t & 63, w = t >> 6;
  int v = (t<nb) ? histsT[d*MAXBUK + t] : 0;
  int x = v;
  #pragma unroll
  for (int off=1; off<64; off<<=1){
    int y = __shfl_up(x, off);
    if (lane >= off) x += y;
  }
  __shared__ int ws[8];
  if (lane==63) ws[w] = x;
  __syncthreads();
  int wo = 0;
  #pragma unroll
  for (int i=0;i<8;i++) if (i<w) wo += ws[i];
  if (t<nb) histsT[d*MAXBUK + t] = wo + x - v;   // exclusive
  if (t==511) bintot[d] = wo + x;                // bin total
}

__global__ void k_dscatter2(const int* __restrict__ deg, int N,
                            const int* __restrict__ histsT, const int* __restrict__ base,
                            int* __restrict__ perm){
  __shared__ int lh[256];
  int t = threadIdx.x, b = blockIdx.x;   // 128 threads, one bucket per block
  lh[t] = 0; lh[t+128] = 0;
  __syncthreads();
  int i = (b<<BUKSH) + t;
  if (i < N){
    int d = min(deg[i],255);
    int r = atomicAdd(&lh[d], 1);
    perm[base[d] + histsT[d*MAXBUK + b] + r] = i;
  }
}

// ------------- weight prep: Wl/Wr (128x128 f32, k-major) -> Wt fp16 [L][n][k] --
__global__ void k_prep(const float* __restrict__ Wl1, const float* __restrict__ Wr1,
                       const float* __restrict__ Wl2, const float* __restrict__ Wr2,
                       _Float16* __restrict__ Wt){
  int idx = blockIdx.x*256 + threadIdx.x;   // 2*256*128 = 65536 total
  int L   = idx >> 15;
  int rem = idx & 32767;
  int nn  = rem >> 7;        // 0..255
  int k   = rem & 127;
  const float* W = (L==0) ? (nn<H?Wl1:Wr1) : (nn<H?Wl2:Wr2);
  Wt[idx] = (_Float16)W[k*H + (nn&127)];
}

// ---------------- layer-0 K=7 GEMM pair: x fp32 -> xl/xr fp16 ----------------
__global__ void k_gemm7(const float* __restrict__ x,
                        const float* __restrict__ Wl, const float* __restrict__ bl,
                        const float* __restrict__ Wr, const float* __restrict__ br,
                        __half* __restrict__ xl, __half* __restrict__ xr, int n){
  int col = threadIdx.x;            // 0..127
  int n0 = blockIdx.x*8;
  float accl[8], accr[8];
  float bL = bl[col], bR = br[col];
  #pragma unroll
  for (int t=0;t<8;t++){ accl[t]=bL; accr[t]=bR; }
  #pragma unroll
  for (int k=0;k<7;k++){
    float wl = Wl[k*H + col];
    float wr = Wr[k*H + col];
    #pragma unroll
    for (int t=0;t<8;t++){
      int node = n0+t; if (node >= n) node = n-1;
      float hv = x[(size_t)node*7 + k];
      accl[t] = fmaf(hv, wl, accl[t]);
      accr[t] = fmaf(hv, wr, accr[t]);
    }
  }
  #pragma unroll
  for (int t=0;t<8;t++){
    int node = n0+t;
    if (node < n){
      xl[(size_t)node*H + col] = __float2half(accl[t]);
      xr[(size_t)node*H + col] = __float2half(accr[t]);
    }
  }
}

// ------------- MFMA GEMM pair: h[n,128]f16 @ Wt -> xl,xr f16 (f32 accum) ------
__global__ __launch_bounds__(256) void k_gemm2h(
    const __half* __restrict__ h, const _Float16* __restrict__ Wt,
    const float* __restrict__ bl, const float* __restrict__ br,
    __half* __restrict__ xl, __half* __restrict__ xr, int n){
  int wave = threadIdx.x >> 6, lane = threadIdx.x & 63;
  int m16 = lane & 15, quad = lane >> 4;
  int row0 = blockIdx.x*64 + wave*16;
  int arow = row0 + m16; if (arow >= n) arow = n-1;
  const __half* hr = h + (size_t)arow*H;
  half8 a[4];
  #pragma unroll
  for (int kb=0;kb<4;kb++) a[kb] = *(const half8*)(hr + kb*32 + quad*8);
  floatx4 acc[16];
  #pragma unroll
  for (int t=0;t<16;t++){ floatx4 z = {0.f,0.f,0.f,0.f}; acc[t] = z; }
  #pragma unroll
  for (int nt=0;nt<16;nt++){
    const _Float16* wr_ = Wt + (size_t)(nt*16 + m16)*H;
    #pragma unroll
    for (int kb=0;kb<4;kb++){
      half8 b = *(const half8*)(wr_ + kb*32 + quad*8);
      acc[nt] = __builtin_amdgcn_mfma_f32_16x16x32_f16(a[kb], b, acc[nt], 0,0,0);
    }
  }
  #pragma unroll
  for (int nt=0;nt<16;nt++){
    int c = nt*16 + m16;                 // D col = lane&15
    float bias; __half* dst; int cc;
    if (c < H){ bias = bl[c];   dst = xl; cc = c;   }
    else      { bias = br[c-H]; dst = xr; cc = c-H; }
    #pragma unroll
    for (int r=0;r<4;r++){
      int rw = row0 + quad*4 + r;        // D row = quad*4 + r
      if (rw < n) dst[(size_t)rw*H + cc] = __float2half(acc[nt][r] + bias);
    }
  }
}

// ------------- GATv2: 16 lanes/node, 8 feats/lane, unroll-8, fp32 edge math ---
__global__ void k_gat(const __half* __restrict__ xl, const __half* __restrict__ xr,
                      const float* __restrict__ att, const float* __restrict__ bo,
                      const int* __restrict__ row_ptr, const int* __restrict__ csr_src,
                      const int* __restrict__ perm,
                      __half* __restrict__ hout, int n){
  int gid0 = (int)((blockIdx.x*blockDim.x + threadIdx.x) >> 4);
  int lane16 = threadIdx.x & 15;
  if (gid0 >= n) return;
  int gid = perm[gid0];                  // degree-sorted order
  int f = lane16*8;
  float xrv[8], av[8];
  {
    union { float4 q; __half2 h[4]; } U;
    U.q = *(const float4*)(xr + (size_t)gid*H + f);
    #pragma unroll
    for (int i=0;i<4;i++){ float2 t2 = __half22float2(U.h[i]); xrv[2*i]=t2.x; xrv[2*i+1]=t2.y; }
    float4 a0 = *(const float4*)(att + f);
    float4 a1 = *(const float4*)(att + f + 4);
    av[0]=a0.x; av[1]=a0.y; av[2]=a0.z; av[3]=a0.w;
    av[4]=a1.x; av[5]=a1.y; av[6]=a1.z; av[7]=a1.w;
  }
  float acc[8];
  #pragma unroll
  for (int i=0;i<8;i++) acc[i]=0.f;
  float mmax = -INFINITY, denom = 0.f;
  int beg = row_ptr[gid], end = row_ptr[gid+1];
  int j = beg;
  for (; j+7 < end; j += 8){
    int s[8];
    #pragma unroll
    for (int u=0;u<8;u++) s[u] = csr_src[j+u];
    float4 r[8];
    #pragma unroll
    for (int u=0;u<8;u++) r[u] = *(const float4*)(xl + (size_t)s[u]*H + f);
    float d[8];
    #pragma unroll
    for (int u=0;u<8;u++){
      union { float4 q; __half2 h[4]; } U; U.q = r[u];
      float dd = 0.f;
      #pragma unroll
      for (int i=0;i<4;i++){
        float2 vf = __half22float2(U.h[i]);
        float u0 = vf.x + xrv[2*i];
        float u1 = vf.y + xrv[2*i+1];
        float l0 = fmaf(0.4f, fabsf(u0), 0.6f*u0);   // leaky_relu(u,0.2)
        float l1 = fmaf(0.4f, fabsf(u1), 0.6f*u1);
        dd = fmaf(l0, av[2*i], fmaf(l1, av[2*i+1], dd));
      }
      d[u] = dd;
    }
    #pragma unroll
    for (int u=0;u<8;u++) d[u] = grp16_sum(d[u]);
    float m8 = fmaxf(fmaxf(fmaxf(d[0],d[1]), fmaxf(d[2],d[3])),
                     fmaxf(fmaxf(d[4],d[5]), fmaxf(d[6],d[7])));
    if (m8 > mmax){
      float sc = __expf(mmax - m8);
      #pragma unroll
      for (int i=0;i<8;i++) acc[i] *= sc;
      denom *= sc;
      mmax = m8;
    }
    #pragma unroll
    for (int u=0;u<8;u++){
      float w = __expf(d[u] - mmax);
      denom += w;
      union { float4 q; __half2 h[4]; } U; U.q = r[u];
      #pragma unroll
      for (int i=0;i<4;i++){
        float2 vf = __half22float2(U.h[i]);
        acc[2*i]   = fmaf(w, vf.x, acc[2*i]);
        acc[2*i+1] = fmaf(w, vf.y, acc[2*i+1]);
      }
    }
  }
  for (; j<end; j++){
    int s0 = csr_src[j];
    union { float4 q; __half2 h[4]; } U;
    U.q = *(const float4*)(xl + (size_t)s0*H + f);
    float v0[8];
    #pragma unroll
    for (int i=0;i<4;i++){ float2 t0 = __half22float2(U.h[i]); v0[2*i]=t0.x; v0[2*i+1]=t0.y; }
    float dd = 0.f;
    #pragma unroll
    for (int i=0;i<8;i++){
      float u0 = v0[i] + xrv[i];
      float l0 = fmaf(0.4f, fabsf(u0), 0.6f*u0);
      dd = fmaf(l0, av[i], dd);
    }
    dd = grp16_sum(dd);
    if (dd > mmax){
      float sc = __expf(mmax - dd);
      #pragma unroll
      for (int i=0;i<8;i++) acc[i] *= sc;
      denom *= sc;
      mmax = dd;
    }
    float w = __expf(dd - mmax);
    denom += w;
    #pragma unroll
    for (int i=0;i<8;i++) acc[i] = fmaf(w, v0[i], acc[i]);
  }
  float inv = 1.f/denom;
  float o[8];
  {
    float4 b0 = *(const float4*)(bo + f);
    float4 b1 = *(const float4*)(bo + f + 4);
    float bb[8] = {b0.x,b0.y,b0.z,b0.w,b1.x,b1.y,b1.z,b1.w};
    #pragma unroll
    for (int i=0;i<8;i++){
      float t = acc[i]*inv + bb[i];
      o[i] = t > 0.f ? t : expm1f(t);   // ELU
    }
  }
  union { float4 f4; __half2 h2[4]; } u;
  #pragma unroll
  for (int i=0;i<4;i++) u.h2[i] = __floats2half2_rn(o[2*i], o[2*i+1]);
  *(float4*)(hout + (size_t)gid*H + f) = u.f4;
}

// --------- fused segment mean-pool (sorted batch, binary search) + MLP head ---
__global__ void k_fc(const __half* __restrict__ hbuf, const int* __restrict__ batch, int N,
                     const float* __restrict__ W1, const float* __restrict__ b1,
                     const float* __restrict__ W2, const float* __restrict__ b2,
                     float* __restrict__ out){
  __shared__ float g[H];
  __shared__ float2 part[4][64];
  __shared__ float zs[FCD];
  __shared__ int bounds[2];
  int gi = blockIdx.x;
  int t = threadIdx.x;     // 0..255
  if (t < 2){
    int target = gi + t;
    int lo = 0, hi = N;
    while (lo < hi){ int mid = (lo+hi)>>1; if (batch[mid] < target) lo = mid+1; else hi = mid; }
    bounds[t] = lo;
  }
  __syncthreads();
  int lo = bounds[0], hi = bounds[1];
  int pairc = t & 63, slice = t >> 6;
  float sx = 0.f, sy = 0.f;
  for (int node = lo + slice; node < hi; node += 4){
    float2 f2 = __half22float2(*(const __half2*)(hbuf + (size_t)node*H + pairc*2));
    sx += f2.x; sy += f2.y;
  }
  part[slice][pairc] = make_float2(sx, sy);
  __syncthreads();
  if (t < 64){
    float2 a = part[0][t], b = part[1][t], c = part[2][t], d = part[3][t];
    float cnt = (float)(hi - lo); if (cnt < 1.f) cnt = 1.f;
    float inv = 1.f/cnt;
    g[2*t]   = (a.x+b.x+c.x+d.x)*inv;
    g[2*t+1] = (a.y+b.y+c.y+d.y)*inv;
  }
  __syncthreads();
  float acc = b1[t];
  for (int k=0;k<H;k++) acc = fmaf(g[k], W1[k*FCD+t], acc);
  zs[t] = acc > 0.f ? acc : 0.f;
  __syncthreads();
  if (t < 2){
    float l = b2[t];
    for (int k=0;k<FCD;k++) l = fmaf(zs[k], W2[k*2+t], l);
    g[t] = l;
  }
  __syncthreads();
  if (t < 2){
    float l0 = g[0], l1 = g[1];
    float mx = fmaxf(l0,l1);
    float lse = mx + logf(__expf(l0-mx) + __expf(l1-mx));
    out[gi*2+t] = g[t] - lse;
  }
}

extern "C" void kernel_launch(void* const* d_in, const int* in_sizes, int n_in,
                              void* d_out, int out_size, void* d_ws, size_t ws_size,
                              hipStream_t stream) {
  const float* x     = (const float*)d_in[0];
  const int*   ei    = (const int*)  d_in[1];
  const int*   batch = (const int*)  d_in[2];
  const float* Wl[3]  = {(const float*)d_in[3],  (const float*)d_in[9],  (const float*)d_in[15]};
  const float* bl[3]  = {(const float*)d_in[4],  (const float*)d_in[10], (const float*)d_in[16]};
  const float* Wr[3]  = {(const float*)d_in[5],  (const float*)d_in[11], (const float*)d_in[17]};
  const float* br[3]  = {(const float*)d_in[6],  (const float*)d_in[12], (const float*)d_in[18]};
  const float* att[3] = {(const float*)d_in[7],  (const float*)d_in[13], (const float*)d_in[19]};
  const float* bo[3]  = {(const float*)d_in[8],  (const float*)d_in[14], (const float*)d_in[20]};
  const float* fc1W = (const float*)d_in[21];
  const float* fc1b = (const float*)d_in[22];
  const float* fc2W = (const float*)d_in[23];
  const float* fc2b = (const float*)d_in[24];

  const int N  = in_sizes[2];
  const int E  = in_sizes[1]/2;
  const int Et = E + N;
  const int G  = out_size/2;
  const int NBUK = (N + (1<<BUKSH)-1) >> BUKSH;   // dst buckets (<=512)
  const int NEB = (Et + 8191)/8192;        // edge blocks for bucket kernels

  char* p = (char*)d_ws;
  auto alloc = [&](size_t bytes)->void*{
    void* r = (void*)p; p += (bytes + 255) & ~(size_t)255; return r;
  };
  int*      deg     = (int*)     alloc((size_t)N*4);
  int*      row_ptr = (int*)     alloc((size_t)(N+1)*4);
  int*      bhist   = (int*)     alloc((size_t)(MAXBUK+1)*4);
  int*      bbase   = (int*)     alloc((size_t)(MAXBUK+1)*4);
  int*      bnext   = (int*)     alloc((size_t)(MAXBUK+1)*4);
  int*      histsT  = (int*)     alloc((size_t)256*MAXBUK*4);
  int*      bintot  = (int*)     alloc((size_t)260*4);
  int*      dbase   = (int*)     alloc((size_t)260*4);
  int*      perm    = (int*)     alloc((size_t)N*4);
  int*      csr     = (int*)     alloc((size_t)Et*4);
  unsigned* ebuf    = (unsigned*)alloc((size_t)Et*4);
  __half*   xl      = (__half*)  alloc((size_t)N*H*2);
  __half*   xr      = (__half*)  alloc((size_t)N*H*2);
  __half*   hbuf    = (__half*)  alloc((size_t)N*H*2);
  _Float16* Wt      = (_Float16*)alloc((size_t)2*256*H*2);

  (void)hipMemsetAsync(bhist, 0, (size_t)(MAXBUK+1)*4, stream);
  k_prep<<<256, 256, 0, stream>>>(Wl[1], Wr[1], Wl[2], Wr[2], Wt);

  // ---- bucketed CSR build (fused) ----
  k_bhist   <<<NEB, 512, 0, stream>>>(ei, E, Et, NBUK, bhist);
  k_scan512 <<<1, 512, 0, stream>>>(bhist, NBUK, bbase, bnext);
  k_bscatter<<<NEB, 512, 0, stream>>>(ei, E, Et, NBUK, bnext, ebuf);
  k_bfill   <<<NBUK, 256, 0, stream>>>(ebuf, bbase, N, Et, row_ptr, deg, csr, histsT);
  // ---- degree sort -> perm (zero global atomics, parallel bin scan) ----
  k_dbinscan<<<256, 512, 0, stream>>>(histsT, NBUK, bintot);
  k_scan512 <<<1, 512, 0, stream>>>(bintot, 256, dbase, nullptr);
  k_dscatter2<<<NBUK, 128, 0, stream>>>(deg, N, histsT, dbase, perm);

  const int g7  = (N + 7)/8;
  const int gM  = (N + 63)/64;
  const int gg  = (int)(((size_t)N*16 + 255)/256);

  // layer 0 (K=7)
  k_gemm7<<<g7, 128, 0, stream>>>(x, Wl[0], bl[0], Wr[0], br[0], xl, xr, N);
  k_gat<<<gg, 256, 0, stream>>>(xl, xr, att[0], bo[0], row_ptr, csr, perm, hbuf, N);
  // layer 1
  k_gemm2h<<<gM, 256, 0, stream>>>(hbuf, Wt, bl[1], br[1], xl, xr, N);
  k_gat<<<gg, 256, 0, stream>>>(xl, xr, att[1], bo[1], row_ptr, csr, perm, hbuf, N);
  // layer 2
  k_gemm2h<<<gM, 256, 0, stream>>>(hbuf, Wt + (size_t)256*H, bl[2], br[2], xl, xr, N);
  k_gat<<<gg, 256, 0, stream>>>(xl, xr, att[2], bo[2], row_ptr, csr, perm, hbuf, N);

  // fused pool + head (sorted batch, no atomics)
  k_fc<<<G, 256, 0, stream>>>(hbuf, batch, N, fc1W, fc1b, fc2W, fc2b, (float*)d_out);
}

// Round 12
// 402.398 us; speedup vs baseline: 1.3649x; 1.1447x over previous
//
#include <hip/hip_runtime.h>
#include <hip/hip_fp16.h>
#include <math.h>

#define H 128
#define FCD 256
#define BUKSH 7                    // 128 dst nodes per bucket
#define MAXBUK 512                 // supports N <= 65536

typedef _Float16 half8 __attribute__((ext_vector_type(8)));
typedef float floatx4 __attribute__((ext_vector_type(4)));

// ---------------- DPP 16-lane (row) reduction: 4 VALU adds, no LDS pipe -------
template<int CTRL>
__device__ __forceinline__ float dppadd(float x){
  return x + __int_as_float(__builtin_amdgcn_update_dpp(
      0, __float_as_int(x), CTRL, 0xf, 0xf, true));
}
__device__ __forceinline__ float grp16_sum(float x){
  x = dppadd<0x128>(x);   // row_ror:8
  x = dppadd<0x124>(x);   // row_ror:4
  x = dppadd<0x122>(x);   // row_ror:2
  x = dppadd<0x121>(x);   // row_ror:1
  return x;
}

// ---------------- generic single-block exclusive scan (nb <= 512) -------------
__global__ void k_scan512(const int* __restrict__ in, int nb,
                          int* __restrict__ out1, int* __restrict__ out2){
  int t = threadIdx.x, lane = t & 63, w = t >> 6;
  int v = (t<nb) ? in[t] : 0;
  int x = v;
  #pragma unroll
  for (int off=1; off<64; off<<=1){
    int y = __shfl_up(x, off);
    if (lane >= off) x += y;
  }
  __shared__ int ws[8];
  if (lane==63) ws[w] = x;
  __syncthreads();
  int wo = 0;
  #pragma unroll
  for (int i=0;i<8;i++) if (i<w) wo += ws[i];
  int excl = wo + x - v;
  if (t<nb){ out1[t] = excl; if (out2) out2[t] = excl; }
  if (t==511) out1[nb] = wo + x;
}

// ---------------- bucketed CSR build ----------------
// phase 1: bucket histogram (8192 edges per block)
__global__ void k_bhist(const int* __restrict__ ei, int E, int Et, int nbuk,
                        int* __restrict__ bhist){
  __shared__ int lh[MAXBUK];
  int t = threadIdx.x;
  lh[t] = 0;
  __syncthreads();
  int j0 = blockIdx.x*8192;
  #pragma unroll
  for (int i=0;i<16;i++){
    int j = j0 + i*512 + t;
    if (j < Et){
      int dst = (j < E) ? ei[E+j] : (j - E);
      atomicAdd(&lh[dst>>BUKSH], 1);
    }
  }
  __syncthreads();
  if (t < nbuk && lh[t]) atomicAdd(&bhist[t], lh[t]);
}

// phase 2: scatter packed edges into bucket-contiguous ebuf
__global__ void k_bscatter(const int* __restrict__ ei, int E, int Et, int nbuk,
                           int* __restrict__ bnext, unsigned* __restrict__ ebuf){
  __shared__ int lh[MAXBUK];
  __shared__ int lbase[MAXBUK];
  int t = threadIdx.x;
  lh[t] = 0;
  __syncthreads();
  int j0 = blockIdx.x*8192;
  unsigned pk[16]; int bk[16]; int rk[16];
  #pragma unroll
  for (int i=0;i<16;i++){
    int j = j0 + i*512 + t;
    if (j < Et){
      int src, dst;
      if (j < E){ src = ei[j]; dst = ei[E+j]; } else { src = dst = j - E; }
      pk[i] = (unsigned)src | ((unsigned)dst << 16);
      bk[i] = dst >> BUKSH;
      rk[i] = atomicAdd(&lh[bk[i]], 1);
    }
  }
  __syncthreads();
  if (t < nbuk){
    int c = lh[t];
    lbase[t] = c ? atomicAdd(&bnext[t], c) : 0;
  }
  __syncthreads();
  #pragma unroll
  for (int i=0;i<16;i++){
    int j = j0 + i*512 + t;
    if (j < Et) ebuf[lbase[bk[i]] + rk[i]] = pk[i];
  }
}

// phase 3 (fused): bucket b's edges occupy ebuf[bbase[b]:bbase[b+1]] == its CSR
// range. count(LDS) -> 128-wide scan -> row_ptr/deg/degree-hist(T) -> CSR fill.
// csr entries stored as BYTE offsets (src*256) for k_gat address math.
__global__ void k_bfill(const unsigned* __restrict__ ebuf, const int* __restrict__ bbase,
                        int N, int Et,
                        int* __restrict__ row_ptr, int* __restrict__ deg,
                        int* __restrict__ csr, int* __restrict__ histsT){
  __shared__ int cnt[1<<BUKSH];
  __shared__ int lnxt[1<<BUKSH];
  __shared__ int bh[256];
  __shared__ int ws0[1];
  int b = blockIdx.x, t = threadIdx.x;
  if (t < (1<<BUKSH)) cnt[t] = 0;
  bh[t] = 0;
  if (b==0 && t==0) row_ptr[N] = Et;      // R8 fix carried forward
  __syncthreads();
  int lo = bbase[b], hi = bbase[b+1];
  for (int j = lo + t; j < hi; j += 256){
    unsigned d = ebuf[j] >> 16;
    atomicAdd(&cnt[d & ((1<<BUKSH)-1)], 1);
  }
  __syncthreads();
  // 128-wide inclusive scan (2 waves)
  int lane = t & 63;
  int v = (t < (1<<BUKSH)) ? cnt[t] : 0;
  int x = v;
  #pragma unroll
  for (int off=1; off<64; off<<=1){
    int y = __shfl_up(x, off);
    if (lane >= off) x += y;
  }
  if (t==63) ws0[0] = x;
  __syncthreads();
  if (t >= 64 && t < 128) x += ws0[0];
  if (t < (1<<BUKSH)){
    int node = (b<<BUKSH) + t;
    int excl = lo + x - v;
    lnxt[t] = excl;
    if (node < N){
      row_ptr[node] = excl;
      deg[node] = v;
      atomicAdd(&bh[min(v,255)], 1);     // per-bucket degree histogram
    }
  }
  __syncthreads();
  histsT[t*MAXBUK + b] = bh[t];          // TRANSPOSED: bin-major for k_dbinscan
  for (int j = lo + t; j < hi; j += 256){
    unsigned e = ebuf[j];
    int d = (e >> 16) & ((1<<BUKSH)-1);
    int r = atomicAdd(&lnxt[d], 1);
    csr[r] = (int)((e & 0xffff) << 8);   // byte offset: src * H * sizeof(half)
  }
}

// ------- degree sort: parallel per-bin scan; one block per degree bin d -------
__global__ void k_dbinscan(int* __restrict__ histsT, int nb, int* __restrict__ bintot){
  int d = blockIdx.x;
  int t = threadIdx.x, lane = t & 63, w = t >> 6;
  int v = (t<nb) ? histsT[d*MAXBUK + t] : 0;
  int x = v;
  #pragma unroll
  for (int off=1; off<64; off<<=1){
    int y = __shfl_up(x, off);
    if (lane >= off) x += y;
  }
  __shared__ int ws[8];
  if (lane==63) ws[w] = x;
  __syncthreads();
  int wo = 0;
  #pragma unroll
  for (int i=0;i<8;i++) if (i<w) wo += ws[i];
  if (t<nb) histsT[d*MAXBUK + t] = wo + x - v;   // exclusive
  if (t==511) bintot[d] = wo + x;                // bin total
}

// scatter with inline 256-bin base scan (R12: removes a k_scan512 dispatch)
__global__ void k_dscatter2(const int* __restrict__ deg, int N,
                            const int* __restrict__ histsT, const int* __restrict__ bintot,
                            int* __restrict__ perm){
  __shared__ int lh[256];
  __shared__ int sbase[256];
  __shared__ int ws[4];
  int t = threadIdx.x, b = blockIdx.x;   // 256 threads, one bucket per block
  int lane = t & 63, w = t >> 6;
  int v = bintot[t];
  int x = v;
  #pragma unroll
  for (int off=1; off<64; off<<=1){
    int y = __shfl_up(x, off);
    if (lane >= off) x += y;
  }
  if (lane==63) ws[w] = x;
  lh[t] = 0;
  __syncthreads();
  int wo = (w>0?ws[0]:0) + (w>1?ws[1]:0) + (w>2?ws[2]:0);
  sbase[t] = wo + x - v;                 // exclusive scan of bintot
  __syncthreads();
  if (t < 128){
    int i = (b<<BUKSH) + t;
    if (i < N){
      int d = min(deg[i],255);
      int r = atomicAdd(&lh[d], 1);
      perm[sbase[d] + histsT[d*MAXBUK + b] + r] = i;
    }
  }
}

// ------- weight prep: swizzle Wl/Wr to MFMA-fragment-linear fp16 layout -------
// Wt[((L*16+nt)*4+kb)*512 + lane*8 + e] = W[k=kb*32+(lane>>4)*8+e][n=nt*16+(lane&15)]
// -> k_gemm2h B loads become fully lane-contiguous (1 KB/wave instruction).
// block 0 also zeroes bhist (replaces a hipMemsetAsync dispatch).
__global__ void k_prep(const float* __restrict__ Wl1, const float* __restrict__ Wr1,
                       const float* __restrict__ Wl2, const float* __restrict__ Wr2,
                       _Float16* __restrict__ Wt, int* __restrict__ bhist){
  int idx = blockIdx.x*256 + threadIdx.x;   // 2*16*4*512 = 65536 total
  if (blockIdx.x == 0){
    for (int i = threadIdx.x; i <= MAXBUK; i += 256) bhist[i] = 0;
  }
  int e    = idx & 7;
  int lane = (idx >> 3) & 63;
  int kb   = (idx >> 9) & 3;
  int nt   = (idx >> 11) & 15;
  int L    = idx >> 15;
  int m16 = lane & 15, quad = lane >> 4;
  int k = kb*32 + quad*8 + e;
  int n = nt*16 + m16;
  const float* W = (L==0) ? (n<H?Wl1:Wr1) : (n<H?Wl2:Wr2);
  Wt[idx] = (_Float16)W[k*H + (n&127)];
}

// ---------------- layer-0 K=7 GEMM pair: x fp32 -> xl/xr fp16 ----------------
__global__ void k_gemm7(const float* __restrict__ x,
                        const float* __restrict__ Wl, const float* __restrict__ bl,
                        const float* __restrict__ Wr, const float* __restrict__ br,
                        __half* __restrict__ xl, __half* __restrict__ xr, int n){
  int col = threadIdx.x;            // 0..127
  int n0 = blockIdx.x*8;
  float accl[8], accr[8];
  float bL = bl[col], bR = br[col];
  #pragma unroll
  for (int t=0;t<8;t++){ accl[t]=bL; accr[t]=bR; }
  #pragma unroll
  for (int k=0;k<7;k++){
    float wl = Wl[k*H + col];
    float wr = Wr[k*H + col];
    #pragma unroll
    for (int t=0;t<8;t++){
      int node = n0+t; if (node >= n) node = n-1;
      float hv = x[(size_t)node*7 + k];
      accl[t] = fmaf(hv, wl, accl[t]);
      accr[t] = fmaf(hv, wr, accr[t]);
    }
  }
  #pragma unroll
  for (int t=0;t<8;t++){
    int node = n0+t;
    if (node < n){
      xl[(size_t)node*H + col] = __float2half(accl[t]);
      xr[(size_t)node*H + col] = __float2half(accr[t]);
    }
  }
}

// ------------- MFMA GEMM pair: h[n,128]f16 @ Wt -> xl,xr f16 (f32 accum) ------
__global__ __launch_bounds__(256) void k_gemm2h(
    const __half* __restrict__ h, const _Float16* __restrict__ Wt,
    const float* __restrict__ bl, const float* __restrict__ br,
    __half* __restrict__ xl, __half* __restrict__ xr, int n){
  int wave = threadIdx.x >> 6, lane = threadIdx.x & 63;
  int m16 = lane & 15, quad = lane >> 4;
  int row0 = blockIdx.x*64 + wave*16;
  int arow = row0 + m16; if (arow >= n) arow = n-1;
  const __half* hr = h + (size_t)arow*H;
  half8 a[4];
  #pragma unroll
  for (int kb=0;kb<4;kb++) a[kb] = *(const half8*)(hr + kb*32 + quad*8);
  floatx4 acc[16];
  #pragma unroll
  for (int t=0;t<16;t++){ floatx4 z = {0.f,0.f,0.f,0.f}; acc[t] = z; }
  #pragma unroll
  for (int nt=0;nt<16;nt++){
    const _Float16* bp = Wt + ((size_t)nt*4)*512 + lane*8;
    #pragma unroll
    for (int kb=0;kb<4;kb++){
      half8 b = *(const half8*)(bp + kb*512);
      acc[nt] = __builtin_amdgcn_mfma_f32_16x16x32_f16(a[kb], b, acc[nt], 0,0,0);
    }
  }
  #pragma unroll
  for (int nt=0;nt<16;nt++){
    int c = nt*16 + m16;                 // D col = lane&15
    float bias; __half* dst; int cc;
    if (c < H){ bias = bl[c];   dst = xl; cc = c;   }
    else      { bias = br[c-H]; dst = xr; cc = c-H; }
    #pragma unroll
    for (int r=0;r<4;r++){
      int rw = row0 + quad*4 + r;        // D row = quad*4 + r
      if (rw < n) dst[(size_t)rw*H + cc] = __float2half(acc[nt][r] + bias);
    }
  }
}

// ------------- GATv2: 16 lanes/node, 8 feats/lane, unroll-8, fp32 edge math ---
// leaky(u)=0.6u+0.4|u| distributed over the dot: d = 0.6*(u.a) + 0.4*(|u|.a)
// (abs is a free VOP3 input modifier). Descending-degree dispatch order.
__global__ void k_gat(const __half* __restrict__ xl, const __half* __restrict__ xr,
                      const float* __restrict__ att, const float* __restrict__ bo,
                      const int* __restrict__ row_ptr, const int* __restrict__ csr_src,
                      const int* __restrict__ perm,
                      __half* __restrict__ hout, int n){
  int gid0 = (int)((blockIdx.x*blockDim.x + threadIdx.x) >> 4);
  int lane16 = threadIdx.x & 15;
  if (gid0 >= n) return;
  int gid = perm[n-1-gid0];              // descending degree: long blocks first
  const char* xlb = (const char*)xl + lane16*16;
  int f = lane16*8;
  float xrv[8], av[8];
  {
    union { float4 q; __half2 h[4]; } U;
    U.q = *(const float4*)(xr + (size_t)gid*H + f);
    #pragma unroll
    for (int i=0;i<4;i++){ float2 t2 = __half22float2(U.h[i]); xrv[2*i]=t2.x; xrv[2*i+1]=t2.y; }
    float4 a0 = *(const float4*)(att + f);
    float4 a1 = *(const float4*)(att + f + 4);
    av[0]=a0.x; av[1]=a0.y; av[2]=a0.z; av[3]=a0.w;
    av[4]=a1.x; av[5]=a1.y; av[6]=a1.z; av[7]=a1.w;
  }
  float acc[8];
  #pragma unroll
  for (int i=0;i<8;i++) acc[i]=0.f;
  float mmax = -INFINITY, denom = 0.f;
  int beg = row_ptr[gid], end = row_ptr[gid+1];
  int j = beg;
  for (; j+7 < end; j += 8){
    int s[8];
    #pragma unroll
    for (int u=0;u<8;u++) s[u] = csr_src[j+u];      // byte offsets
    float4 r[8];
    #pragma unroll
    for (int u=0;u<8;u++) r[u] = *(const float4*)(xlb + s[u]);
    float d[8];
    #pragma unroll
    for (int u=0;u<8;u++){
      union { float4 q; __half2 h[4]; } U; U.q = r[u];
      float pp = 0.f, qq = 0.f;
      #pragma unroll
      for (int i=0;i<4;i++){
        float2 vf = __half22float2(U.h[i]);
        float u0 = vf.x + xrv[2*i];
        float u1 = vf.y + xrv[2*i+1];
        pp = fmaf(u0, av[2*i], pp);  qq = fmaf(fabsf(u0), av[2*i], qq);
        pp = fmaf(u1, av[2*i+1], pp); qq = fmaf(fabsf(u1), av[2*i+1], qq);
      }
      d[u] = fmaf(0.6f, pp, 0.4f*qq);
    }
    #pragma unroll
    for (int u=0;u<8;u++) d[u] = grp16_sum(d[u]);
    float m8 = fmaxf(fmaxf(fmaxf(d[0],d[1]), fmaxf(d[2],d[3])),
                     fmaxf(fmaxf(d[4],d[5]), fmaxf(d[6],d[7])));
    if (m8 > mmax){
      float sc = __expf(mmax - m8);
      #pragma unroll
      for (int i=0;i<8;i++) acc[i] *= sc;
      denom *= sc;
      mmax = m8;
    }
    #pragma unroll
    for (int u=0;u<8;u++){
      float w = __expf(d[u] - mmax);
      denom += w;
      union { float4 q; __half2 h[4]; } U; U.q = r[u];
      #pragma unroll
      for (int i=0;i<4;i++){
        float2 vf = __half22float2(U.h[i]);
        acc[2*i]   = fmaf(w, vf.x, acc[2*i]);
        acc[2*i+1] = fmaf(w, vf.y, acc[2*i+1]);
      }
    }
  }
  for (; j<end; j++){
    int s0 = csr_src[j];
    union { float4 q; __half2 h[4]; } U;
    U.q = *(const float4*)(xlb + s0);
    float v0[8];
    #pragma unroll
    for (int i=0;i<4;i++){ float2 t0 = __half22float2(U.h[i]); v0[2*i]=t0.x; v0[2*i+1]=t0.y; }
    float pp = 0.f, qq = 0.f;
    #pragma unroll
    for (int i=0;i<8;i++){
      float u0 = v0[i] + xrv[i];
      pp = fmaf(u0, av[i], pp);  qq = fmaf(fabsf(u0), av[i], qq);
    }
    float dd = fmaf(0.6f, pp, 0.4f*qq);
    dd = grp16_sum(dd);
    if (dd > mmax){
      float sc = __expf(mmax - dd);
      #pragma unroll
      for (int i=0;i<8;i++) acc[i] *= sc;
      denom *= sc;
      mmax = dd;
    }
    float w = __expf(dd - mmax);
    denom += w;
    #pragma unroll
    for (int i=0;i<8;i++) acc[i] = fmaf(w, v0[i], acc[i]);
  }
  float inv = 1.f/denom;
  float o[8];
  {
    float4 b0 = *(const float4*)(bo + f);
    float4 b1 = *(const float4*)(bo + f + 4);
    float bb[8] = {b0.x,b0.y,b0.z,b0.w,b1.x,b1.y,b1.z,b1.w};
    #pragma unroll
    for (int i=0;i<8;i++){
      float t = acc[i]*inv + bb[i];
      o[i] = t > 0.f ? t : expm1f(t);   // ELU
    }
  }
  union { float4 f4; __half2 h2[4]; } u;
  #pragma unroll
  for (int i=0;i<4;i++) u.h2[i] = __floats2half2_rn(o[2*i], o[2*i+1]);
  *(float4*)(hout + (size_t)gid*H + f) = u.f4;
}

// --------- fused segment mean-pool (sorted batch, binary search) + MLP head ---
__global__ void k_fc(const __half* __restrict__ hbuf, const int* __restrict__ batch, int N,
                     const float* __restrict__ W1, const float* __restrict__ b1,
                     const float* __restrict__ W2, const float* __restrict__ b2,
                     float* __restrict__ out){
  __shared__ float g[H];
  __shared__ float2 part[4][64];
  __shared__ float zs[FCD];
  __shared__ int bounds[2];
  int gi = blockIdx.x;
  int t = threadIdx.x;     // 0..255
  if (t < 2){
    int target = gi + t;
    int lo = 0, hi = N;
    while (lo < hi){ int mid = (lo+hi)>>1; if (batch[mid] < target) lo = mid+1; else hi = mid; }
    bounds[t] = lo;
  }
  __syncthreads();
  int lo = bounds[0], hi = bounds[1];
  int pairc = t & 63, slice = t >> 6;
  float sx = 0.f, sy = 0.f;
  for (int node = lo + slice; node < hi; node += 4){
    float2 f2 = __half22float2(*(const __half2*)(hbuf + (size_t)node*H + pairc*2));
    sx += f2.x; sy += f2.y;
  }
  part[slice][pairc] = make_float2(sx, sy);
  __syncthreads();
  if (t < 64){
    float2 a = part[0][t], b = part[1][t], c = part[2][t], d = part[3][t];
    float cnt = (float)(hi - lo); if (cnt < 1.f) cnt = 1.f;
    float inv = 1.f/cnt;
    g[2*t]   = (a.x+b.x+c.x+d.x)*inv;
    g[2*t+1] = (a.y+b.y+c.y+d.y)*inv;
  }
  __syncthreads();
  float acc = b1[t];
  for (int k=0;k<H;k++) acc = fmaf(g[k], W1[k*FCD+t], acc);
  zs[t] = acc > 0.f ? acc : 0.f;
  __syncthreads();
  if (t < 2){
    float l = b2[t];
    for (int k=0;k<FCD;k++) l = fmaf(zs[k], W2[k*2+t], l);
    g[t] = l;
  }
  __syncthreads();
  if (t < 2){
    float l0 = g[0], l1 = g[1];
    float mx = fmaxf(l0,l1);
    float lse = mx + logf(__expf(l0-mx) + __expf(l1-mx));
    out[gi*2+t] = g[t] - lse;
  }
}

extern "C" void kernel_launch(void* const* d_in, const int* in_sizes, int n_in,
                              void* d_out, int out_size, void* d_ws, size_t ws_size,
                              hipStream_t stream) {
  const float* x     = (const float*)d_in[0];
  const int*   ei    = (const int*)  d_in[1];
  const int*   batch = (const int*)  d_in[2];
  const float* Wl[3]  = {(const float*)d_in[3],  (const float*)d_in[9],  (const float*)d_in[15]};
  const float* bl[3]  = {(const float*)d_in[4],  (const float*)d_in[10], (const float*)d_in[16]};
  const float* Wr[3]  = {(const float*)d_in[5],  (const float*)d_in[11], (const float*)d_in[17]};
  const float* br[3]  = {(const float*)d_in[6],  (const float*)d_in[12], (const float*)d_in[18]};
  const float* att[3] = {(const float*)d_in[7],  (const float*)d_in[13], (const float*)d_in[19]};
  const float* bo[3]  = {(const float*)d_in[8],  (const float*)d_in[14], (const float*)d_in[20]};
  const float* fc1W = (const float*)d_in[21];
  const float* fc1b = (const float*)d_in[22];
  const float* fc2W = (const float*)d_in[23];
  const float* fc2b = (const float*)d_in[24];

  const int N  = in_sizes[2];
  const int E  = in_sizes[1]/2;
  const int Et = E + N;
  const int G  = out_size/2;
  const int NBUK = (N + (1<<BUKSH)-1) >> BUKSH;   // dst buckets (<=512)
  const int NEB = (Et + 8191)/8192;        // edge blocks for bucket kernels

  char* p = (char*)d_ws;
  auto alloc = [&](size_t bytes)->void*{
    void* r = (void*)p; p += (bytes + 255) & ~(size_t)255; return r;
  };
  int*      deg     = (int*)     alloc((size_t)N*4);
  int*      row_ptr = (int*)     alloc((size_t)(N+1)*4);
  int*      bhist   = (int*)     alloc((size_t)(MAXBUK+1)*4);
  int*      bbase   = (int*)     alloc((size_t)(MAXBUK+1)*4);
  int*      bnext   = (int*)     alloc((size_t)(MAXBUK+1)*4);
  int*      histsT  = (int*)     alloc((size_t)256*MAXBUK*4);
  int*      bintot  = (int*)     alloc((size_t)260*4);
  int*      perm    = (int*)     alloc((size_t)N*4);
  int*      csr     = (int*)     alloc((size_t)Et*4);
  unsigned* ebuf    = (unsigned*)alloc((size_t)Et*4);
  __half*   xl      = (__half*)  alloc((size_t)N*H*2);
  __half*   xr      = (__half*)  alloc((size_t)N*H*2);
  __half*   hbuf    = (__half*)  alloc((size_t)N*H*2);
  _Float16* Wt      = (_Float16*)alloc((size_t)2*16*4*512*2);

  // prep (also zeroes bhist)
  k_prep<<<256, 256, 0, stream>>>(Wl[1], Wr[1], Wl[2], Wr[2], Wt, bhist);

  // ---- bucketed CSR build (fused) ----
  k_bhist   <<<NEB, 512, 0, stream>>>(ei, E, Et, NBUK, bhist);
  k_scan512 <<<1, 512, 0, stream>>>(bhist, NBUK, bbase, bnext);
  k_bscatter<<<NEB, 512, 0, stream>>>(ei, E, Et, NBUK, bnext, ebuf);
  k_bfill   <<<NBUK, 256, 0, stream>>>(ebuf, bbase, N, Et, row_ptr, deg, csr, histsT);
  // ---- degree sort -> perm (zero global atomics, parallel bin scan) ----
  k_dbinscan<<<256, 512, 0, stream>>>(histsT, NBUK, bintot);
  k_dscatter2<<<NBUK, 256, 0, stream>>>(deg, N, histsT, bintot, perm);

  const int g7  = (N + 7)/8;
  const int gM  = (N + 63)/64;
  const int gg  = (int)(((size_t)N*16 + 255)/256);

  // layer 0 (K=7)
  k_gemm7<<<g7, 128, 0, stream>>>(x, Wl[0], bl[0], Wr[0], br[0], xl, xr, N);
  k_gat<<<gg, 256, 0, stream>>>(xl, xr, att[0], bo[0], row_ptr, csr, perm, hbuf, N);
  // layer 1
  k_gemm2h<<<gM, 256, 0, stream>>>(hbuf, Wt, bl[1], br[1], xl, xr, N);
  k_gat<<<gg, 256, 0, stream>>>(xl, xr, att[1], bo[1], row_ptr, csr, perm, hbuf, N);
  // layer 2
  k_gemm2h<<<gM, 256, 0, stream>>>(hbuf, Wt + (size_t)16*4*512, bl[2], br[2], xl, xr, N);
  k_gat<<<gg, 256, 0, stream>>>(xl, xr, att[2], bo[2], row_ptr, csr, perm, hbuf, N);

  // fused pool + head (sorted batch, no atomics)
  k_fc<<<G, 256, 0, stream>>>(hbuf, batch, N, fc1W, fc1b, fc2W, fc2b, (float*)d_out);
}